// Round 5
// baseline (903.318 us; speedup 1.0000x reference)
//
#include <hip/hip_runtime.h>
#include <math.h>

#define F_IN 1433
#define F_HID 16
#define F_OUT 7
#define KSPLIT 8
#define KCHUNK 192  // KSPLIT*KCHUNK >= F_IN; multiples of 32

#define AS1 __attribute__((address_space(1)))
#define AS3 __attribute__((address_space(3)))

__device__ __forceinline__ void gload_lds4(const float* gp, float* lp) {
  __builtin_amdgcn_global_load_lds((const AS1 void*)gp, (AS3 void*)lp, 4, 0, 0);
}

__device__ __forceinline__ unsigned short f2bf(float f) {
  unsigned u = __float_as_uint(f);
  u += 0x7fffu + ((u >> 16) & 1u);  // RNE
  return (unsigned short)(u >> 16);
}

__device__ __forceinline__ float bf2f(unsigned short v) {
  return __uint_as_float((unsigned)v << 16);
}

// ---------------- zero int counters ----------------
__global__ __launch_bounds__(256) void k_zero(int* __restrict__ cnt, int N) {
  int i = blockIdx.x * 256 + threadIdx.x;
  if (i < N) cnt[i] = 0;
}

// ---------------- in-degree histogram (int4 edge reads) ----------------
__global__ __launch_bounds__(256) void k_hist(const int* __restrict__ dst,
                                              int* __restrict__ cnt, int E) {
  int e4 = blockIdx.x * 256 + threadIdx.x;
  int base = e4 * 4;
  if (base + 3 < E) {
    const int4 d = *(const int4*)(dst + base);
    atomicAdd(&cnt[d.x], 1);
    atomicAdd(&cnt[d.y], 1);
    atomicAdd(&cnt[d.z], 1);
    atomicAdd(&cnt[d.w], 1);
  } else {
    for (int k = base; k < E; ++k) atomicAdd(&cnt[dst[k]], 1);
  }
}

// ---------------- scan step 1: per-1024-block exclusive scan ----------------
__global__ __launch_bounds__(256) void k_scan1(const int* __restrict__ cnt,
                                               int* __restrict__ offs,
                                               int* __restrict__ bsums, int N) {
  __shared__ int sh[256];
  const int b = blockIdx.x, t = threadIdx.x;
  const int base = b * 1024 + t * 4;
  int v0 = 0, v1 = 0, v2 = 0, v3 = 0;
  if (base + 0 < N) v0 = cnt[base + 0];
  if (base + 1 < N) v1 = cnt[base + 1];
  if (base + 2 < N) v2 = cnt[base + 2];
  if (base + 3 < N) v3 = cnt[base + 3];
  const int s = v0 + v1 + v2 + v3;
  sh[t] = s;
  __syncthreads();
  for (int d = 1; d < 256; d <<= 1) {
    int x = (t >= d) ? sh[t - d] : 0;
    __syncthreads();
    sh[t] += x;
    __syncthreads();
  }
  const int incl = sh[t];
  const int excl = incl - s;
  if (t == 255) bsums[b] = incl;
  int o = excl;
  if (base + 0 < N) offs[base + 0] = o;
  o += v0;
  if (base + 1 < N) offs[base + 1] = o;
  o += v1;
  if (base + 2 < N) offs[base + 2] = o;
  o += v2;
  if (base + 3 < N) offs[base + 3] = o;
}

// ---------------- scan step 2: scan the block sums (1 block) ----------------
__global__ __launch_bounds__(1024) void k_scan2(int* __restrict__ bsums, int nb) {
  __shared__ int sh[1024];
  const int t = threadIdx.x;
  const int v = (t < nb) ? bsums[t] : 0;
  sh[t] = v;
  __syncthreads();
  for (int d = 1; d < 1024; d <<= 1) {
    int x = (t >= d) ? sh[t - d] : 0;
    __syncthreads();
    sh[t] += x;
    __syncthreads();
  }
  if (t < nb) bsums[t] = sh[t] - v;  // exclusive
}

// ---- scan step 3: finalize offsets, init cursor, dis = rsqrt(deg+1) --------
__global__ __launch_bounds__(256) void k_scan3(int* __restrict__ offs,
                                               int* __restrict__ cursor,
                                               float* __restrict__ dis,
                                               const int* __restrict__ cnt,
                                               const int* __restrict__ bsums,
                                               int N) {
  int i = blockIdx.x * 256 + threadIdx.x;
  if (i >= N) return;
  const int o = offs[i] + bsums[i >> 10];
  offs[i] = o;
  cursor[i] = o;
  dis[i] = rsqrtf((float)(cnt[i] + 1));  // +1 = self-loop
}

// ---------------- CSR scatter (int4 edge reads) ----------------
__global__ __launch_bounds__(256) void k_scatter(const int* __restrict__ src,
                                                 const int* __restrict__ dst,
                                                 int* __restrict__ cursor,
                                                 int* __restrict__ csr, int E) {
  int e4 = blockIdx.x * 256 + threadIdx.x;
  int base = e4 * 4;
  if (base + 3 < E) {
    const int4 s = *(const int4*)(src + base);
    const int4 d = *(const int4*)(dst + base);
    csr[atomicAdd(&cursor[d.x], 1)] = s.x;
    csr[atomicAdd(&cursor[d.y], 1)] = s.y;
    csr[atomicAdd(&cursor[d.z], 1)] = s.z;
    csr[atomicAdd(&cursor[d.w], 1)] = s.w;
  } else {
    for (int k = base; k < E; ++k)
      csr[atomicAdd(&cursor[dst[k]], 1)] = src[k];
  }
}

// ---- GEMM1 (K-split, async LDS staging, XOR-swizzled tile) -----------------
// part[c][row][j] = sum_{k in chunk c} x[row][k] * W1[k][j]
// LDS layout: xs[row][col] linear 256x32 (32KB); logical col m stored at
// position m ^ (row&31). global_load_lds writes linearly (lane*4B), so the
// GLOBAL source column is pre-swizzled (m173/rule-21 pattern); reads apply
// the same XOR -> conflict-free (2 lanes/bank, free per m136).
__global__ __launch_bounds__(256) void k_gemm1(const float* __restrict__ x,
                                               const float* __restrict__ W1,
                                               float* __restrict__ part, int N) {
  __shared__ float xs[256 * 32];
  const int t = threadIdx.x;
  const int w = t >> 6;   // wave 0..3
  const int l = t & 63;   // lane
  const int lh = l >> 5;  // half-wave row
  const int kk = l & 31;  // col within tile
  const int row0 = blockIdx.x * 256;
  const int cbase = blockIdx.y * KCHUNK;
  const int kend = min(cbase + KCHUNK, F_IN);

  float acc[F_HID];
#pragma unroll
  for (int j = 0; j < F_HID; ++j) acc[j] = 0.0f;

  for (int k0 = cbase; k0 < kend; k0 += 32) {
    const int kw = kend - k0;
    if (kw >= 32) {
      // async stage: wave w covers rows [64w, 64w+64), 2 rows per instr
#pragma unroll
      for (int i = 0; i < 32; ++i) {
        const int rl0 = w * 64 + 2 * i;       // wave-uniform
        const int rl = rl0 + lh;              // per-lane row
        const int rg = row0 + rl;
        const float* gp =
            x + (size_t)rg * F_IN + k0 + (kk ^ (rl & 31));  // pre-swizzled col
        if (rg < N) gload_lds4(gp, xs + rl0 * 32);
      }
      __syncthreads();  // compiler emits vmcnt(0) before s_barrier -> data ready
#pragma unroll
      for (int c = 0; c < 32; ++c) {
        const float xv = xs[(t << 5) + (c ^ (t & 31))];
        const float* __restrict__ wp = W1 + (size_t)(k0 + c) * F_HID;
#pragma unroll
        for (int j = 0; j < F_HID; ++j)
          acc[j] = fmaf(xv, wp[j], acc[j]);
      }
      __syncthreads();
    } else {
      // partial tail tile: reg-stage with swizzled ds_write, zero-padded
      const int r0 = t >> 5;
#pragma unroll
      for (int i = 0; i < 32; ++i) {
        const int rl = r0 + 8 * i;
        const int rg = row0 + rl;
        float v = (kk < kw && rg < N) ? x[(size_t)rg * F_IN + k0 + kk] : 0.0f;
        xs[rl * 32 + (kk ^ (rl & 31))] = v;
      }
      __syncthreads();
      for (int c = 0; c < kw; ++c) {
        const float xv = xs[(t << 5) + (c ^ (t & 31))];
        const float* __restrict__ wp = W1 + (size_t)(k0 + c) * F_HID;
#pragma unroll
        for (int j = 0; j < F_HID; ++j)
          acc[j] = fmaf(xv, wp[j], acc[j]);
      }
      __syncthreads();
    }
  }

  const int row = row0 + t;
  if (row < N) {
    float4* __restrict__ pp =
        (float4*)(part + ((size_t)blockIdx.y * N + row) * F_HID);
    pp[0] = make_float4(acc[0], acc[1], acc[2], acc[3]);
    pp[1] = make_float4(acc[4], acc[5], acc[6], acc[7]);
    pp[2] = make_float4(acc[8], acc[9], acc[10], acc[11]);
    pp[3] = make_float4(acc[12], acc[13], acc[14], acc[15]);
  }
}

// ---- reduce K-split partials, scale by dis, pack to bf16 -------------------
__global__ __launch_bounds__(256) void k_red(const float4* __restrict__ part,
                                             const float* __restrict__ dis,
                                             uint2* __restrict__ h1b, int N) {
  const int idx = blockIdx.x * 256 + threadIdx.x;  // over N*4 float4s
  if (idx >= N * 4) return;
  const int row = idx >> 2;
  const size_t stride = (size_t)N * 4;
  float4 s = part[idx];
#pragma unroll
  for (int c = 1; c < KSPLIT; ++c) {
    const float4 p = part[c * stride + idx];
    s.x += p.x; s.y += p.y; s.z += p.z; s.w += p.w;
  }
  const float sc = dis[row];
  uint2 o;
  o.x = (unsigned)f2bf(s.x * sc) | ((unsigned)f2bf(s.y * sc) << 16);
  o.y = (unsigned)f2bf(s.z * sc) | ((unsigned)f2bf(s.w * sc) << 16);
  h1b[idx] = o;
}

// ---- layer1 gather + node update fused: one wave64 per dst node ------------
// lanes = 4 neighbor-groups x 16 features; h1 stored as bf16
__global__ __launch_bounds__(256) void k_agg1n(
    const int* __restrict__ offs, const int* __restrict__ cnt,
    const int* __restrict__ csr, const unsigned short* __restrict__ h1b,
    const float* __restrict__ dis, const float* __restrict__ b1,
    const float* __restrict__ W2, float* __restrict__ h2s, int N) {
  const int lane = threadIdx.x & 63;
  const int i = blockIdx.x * 4 + (threadIdx.x >> 6);
  if (i >= N) return;
  const int nb = lane >> 4;
  const int f = lane & 15;

  const int o0 = offs[i];
  const int cend = o0 + cnt[i];
  int c = o0 + nb;
  float acc = 0.0f;
  // unroll-2: two independent gathers in flight
  for (; c + 4 < cend; c += 8) {
    const int sa = csr[c];
    const int sb = csr[c + 4];
    acc += bf2f(h1b[(size_t)sa * F_HID + f]) +
           bf2f(h1b[(size_t)sb * F_HID + f]);
  }
  if (c < cend) acc += bf2f(h1b[(size_t)csr[c] * F_HID + f]);

  acc += __shfl_xor(acc, 16);
  acc += __shfl_xor(acc, 32);

  const float sd = dis[i];
  const float t =
      fmaxf(fmaf(acc + bf2f(h1b[(size_t)i * F_HID + f]), sd, b1[f]), 0.0f);

  float o[F_OUT];
#pragma unroll
  for (int j = 0; j < F_OUT; ++j) o[j] = t * W2[f * F_OUT + j];
#pragma unroll
  for (int dd = 1; dd < 16; dd <<= 1) {
#pragma unroll
    for (int j = 0; j < F_OUT; ++j) o[j] += __shfl_xor(o[j], dd);
  }
  if (lane == 0) {
    float* __restrict__ hp = h2s + (size_t)i * F_OUT;
#pragma unroll
    for (int j = 0; j < F_OUT; ++j) hp[j] = o[j] * sd;
  }
}

// ---- layer2 gather + bias + log_softmax fused: one wave64 per dst ----------
__global__ __launch_bounds__(256) void k_agg2n(const int* __restrict__ offs,
                                               const int* __restrict__ cnt,
                                               const int* __restrict__ csr,
                                               const float* __restrict__ h2s,
                                               const float* __restrict__ dis,
                                               const float* __restrict__ b2,
                                               float* __restrict__ out, int N) {
  const int lane = threadIdx.x & 63;
  const int i = blockIdx.x * 4 + (threadIdx.x >> 6);
  if (i >= N) return;
  const int nb = lane >> 3;
  const int f = lane & 7;

  const int o0 = offs[i];
  const int cend = o0 + cnt[i];
  int c = o0 + nb;
  float acc = 0.0f;
  for (; c + 8 < cend; c += 16) {
    const int sa = csr[c];
    const int sb = csr[c + 8];
    if (f < F_OUT)
      acc += h2s[(size_t)sa * F_OUT + f] + h2s[(size_t)sb * F_OUT + f];
  }
  if (c < cend && f < F_OUT) acc += h2s[(size_t)csr[c] * F_OUT + f];

  acc += __shfl_xor(acc, 8);
  acc += __shfl_xor(acc, 16);
  acc += __shfl_xor(acc, 32);

  float v = -1e30f;
  if (f < F_OUT)
    v = fmaf(acc + h2s[(size_t)i * F_OUT + f], dis[i], b2[f]);

  float m = v;
  m = fmaxf(m, __shfl_xor(m, 1));
  m = fmaxf(m, __shfl_xor(m, 2));
  m = fmaxf(m, __shfl_xor(m, 4));
  float ex = (f < F_OUT) ? expf(v - m) : 0.0f;
  float sum = ex;
  sum += __shfl_xor(sum, 1);
  sum += __shfl_xor(sum, 2);
  sum += __shfl_xor(sum, 4);
  const float r = v - m - logf(sum);
  if (f < F_OUT) out[(size_t)i * F_OUT + f] = r;
}

extern "C" void kernel_launch(void* const* d_in, const int* in_sizes, int n_in,
                              void* d_out, int out_size, void* d_ws,
                              size_t ws_size, hipStream_t stream) {
  const float* x = (const float*)d_in[0];
  const int* ei = (const int*)d_in[1];
  const float* W1 = (const float*)d_in[2];
  const float* b1 = (const float*)d_in[3];
  const float* W2 = (const float*)d_in[4];
  const float* b2 = (const float*)d_in[5];

  const int N = in_sizes[0] / F_IN;
  const int E = in_sizes[1] / 2;
  const int* src = ei;
  const int* dst = ei + E;

  // ws layout (floats): part[128N] | h1b[8N] | h2s[7N] | dis[N] | ints...
  float* part = (float*)d_ws;                               // KSPLIT*16N
  unsigned short* h1b = (unsigned short*)(part + (size_t)KSPLIT * 16 * N);
  float* h2s = (float*)(h1b + (size_t)16 * N);              // 7N
  float* dis = h2s + (size_t)7 * N;                         // N
  int* cnt = (int*)(dis + N);                               // N
  int* offs = cnt + N;                                      // N
  int* cursor = offs + N;                                   // N
  int* bsums = cursor + N;                                  // 1024
  int* csr = (int*)part;  // alias: part fully consumed by k_red before scatter
  float* out = (float*)d_out;

  const int B = 256;
  const int nb_scan = (N + 1023) / 1024;
  const int nrb = (N + 255) / 256;
  const int ne4 = (E + 3) / 4;

  k_zero<<<(N + B - 1) / B, B, 0, stream>>>(cnt, N);
  k_hist<<<(ne4 + B - 1) / B, B, 0, stream>>>(dst, cnt, E);
  k_scan1<<<nb_scan, B, 0, stream>>>(cnt, offs, bsums, N);
  k_scan2<<<1, 1024, 0, stream>>>(bsums, nb_scan);
  k_scan3<<<(N + B - 1) / B, B, 0, stream>>>(offs, cursor, dis, cnt, bsums, N);
  dim3 g1(nrb, KSPLIT);
  k_gemm1<<<g1, 256, 0, stream>>>(x, W1, part, N);
  k_red<<<(N * 4 + B - 1) / B, B, 0, stream>>>((const float4*)part, dis,
                                               (uint2*)h1b, N);
  k_scatter<<<(ne4 + B - 1) / B, B, 0, stream>>>(src, dst, cursor, csr, E);
  k_agg1n<<<(N + 3) / 4, B, 0, stream>>>(offs, cnt, csr, h1b, dis, b1, W2, h2s,
                                         N);
  k_agg2n<<<(N + 3) / 4, B, 0, stream>>>(offs, cnt, csr, h2s, dis, b2, out, N);
}

// Round 6
// 674.425 us; speedup vs baseline: 1.3394x; 1.3394x over previous
//
#include <hip/hip_runtime.h>
#include <math.h>

#define F_IN 1433
#define F_HID 16
#define F_OUT 7
#define KSPLIT 8
#define KCHUNK 192  // KSPLIT*KCHUNK >= F_IN; multiple of 32

__device__ __forceinline__ unsigned short f2bf(float f) {
  unsigned u = __float_as_uint(f);
  u += 0x7fffu + ((u >> 16) & 1u);  // RNE
  return (unsigned short)(u >> 16);
}

__device__ __forceinline__ float bf2f(unsigned short v) {
  return __uint_as_float((unsigned)v << 16);
}

// ---------------- zero int counters ----------------
__global__ __launch_bounds__(256) void k_zero(int* __restrict__ cnt, int N) {
  int i = blockIdx.x * 256 + threadIdx.x;
  if (i < N) cnt[i] = 0;
}

// ---------------- in-degree histogram (int4 edge reads) ----------------
__global__ __launch_bounds__(256) void k_hist(const int* __restrict__ dst,
                                              int* __restrict__ cnt, int E) {
  int e4 = blockIdx.x * 256 + threadIdx.x;
  int base = e4 * 4;
  if (base + 3 < E) {
    const int4 d = *(const int4*)(dst + base);
    atomicAdd(&cnt[d.x], 1);
    atomicAdd(&cnt[d.y], 1);
    atomicAdd(&cnt[d.z], 1);
    atomicAdd(&cnt[d.w], 1);
  } else {
    for (int k = base; k < E; ++k) atomicAdd(&cnt[dst[k]], 1);
  }
}

// ---------------- scan step 1: per-1024-block exclusive scan ----------------
__global__ __launch_bounds__(256) void k_scan1(const int* __restrict__ cnt,
                                               int* __restrict__ offs,
                                               int* __restrict__ bsums, int N) {
  __shared__ int sh[256];
  const int b = blockIdx.x, t = threadIdx.x;
  const int base = b * 1024 + t * 4;
  int v0 = 0, v1 = 0, v2 = 0, v3 = 0;
  if (base + 0 < N) v0 = cnt[base + 0];
  if (base + 1 < N) v1 = cnt[base + 1];
  if (base + 2 < N) v2 = cnt[base + 2];
  if (base + 3 < N) v3 = cnt[base + 3];
  const int s = v0 + v1 + v2 + v3;
  sh[t] = s;
  __syncthreads();
  for (int d = 1; d < 256; d <<= 1) {
    int x = (t >= d) ? sh[t - d] : 0;
    __syncthreads();
    sh[t] += x;
    __syncthreads();
  }
  const int incl = sh[t];
  const int excl = incl - s;
  if (t == 255) bsums[b] = incl;
  int o = excl;
  if (base + 0 < N) offs[base + 0] = o;
  o += v0;
  if (base + 1 < N) offs[base + 1] = o;
  o += v1;
  if (base + 2 < N) offs[base + 2] = o;
  o += v2;
  if (base + 3 < N) offs[base + 3] = o;
}

// ---------------- scan step 2: scan the block sums (1 block) ----------------
__global__ __launch_bounds__(1024) void k_scan2(int* __restrict__ bsums, int nb) {
  __shared__ int sh[1024];
  const int t = threadIdx.x;
  const int v = (t < nb) ? bsums[t] : 0;
  sh[t] = v;
  __syncthreads();
  for (int d = 1; d < 1024; d <<= 1) {
    int x = (t >= d) ? sh[t - d] : 0;
    __syncthreads();
    sh[t] += x;
    __syncthreads();
  }
  if (t < nb) bsums[t] = sh[t] - v;  // exclusive
}

// ---- scan step 3: finalize offsets, init cursor, dis = rsqrt(deg+1) --------
__global__ __launch_bounds__(256) void k_scan3(int* __restrict__ offs,
                                               int* __restrict__ cursor,
                                               float* __restrict__ dis,
                                               const int* __restrict__ cnt,
                                               const int* __restrict__ bsums,
                                               int N) {
  int i = blockIdx.x * 256 + threadIdx.x;
  if (i >= N) return;
  const int o = offs[i] + bsums[i >> 10];
  offs[i] = o;
  cursor[i] = o;
  dis[i] = rsqrtf((float)(cnt[i] + 1));  // +1 = self-loop
}

// ---------------- CSR scatter (int4 edge reads) ----------------
__global__ __launch_bounds__(256) void k_scatter(const int* __restrict__ src,
                                                 const int* __restrict__ dst,
                                                 int* __restrict__ cursor,
                                                 int* __restrict__ csr, int E) {
  int e4 = blockIdx.x * 256 + threadIdx.x;
  int base = e4 * 4;
  if (base + 3 < E) {
    const int4 s = *(const int4*)(src + base);
    const int4 d = *(const int4*)(dst + base);
    csr[atomicAdd(&cursor[d.x], 1)] = s.x;
    csr[atomicAdd(&cursor[d.y], 1)] = s.y;
    csr[atomicAdd(&cursor[d.z], 1)] = s.z;
    csr[atomicAdd(&cursor[d.w], 1)] = s.w;
  } else {
    for (int k = base; k < E; ++k)
      csr[atomicAdd(&cursor[dst[k]], 1)] = src[k];
  }
}

// ---- GEMM1 (K-split): part[c][row][j] = sum_{k in chunk c} x[row][k]*W1[k][j]
// R4-proven structure: reg[32] prefetch double-buffer, pad-33 LDS (reads
// conflict-free: bank = (t+c)%32), scalar-b32 coalesced staging, VGPR ~52.
__global__ __launch_bounds__(256) void k_gemm1(const float* __restrict__ x,
                                               const float* __restrict__ W1,
                                               float* __restrict__ part, int N) {
  __shared__ float xs[256 * 33];
  const int t = threadIdx.x;
  const int row0 = blockIdx.x * 256;
  const int row = row0 + t;
  const int kk = t & 31;
  const int r0 = t >> 5;
  const int cbase = blockIdx.y * KCHUNK;
  const int kend = min(cbase + KCHUNK, F_IN);

  float acc[F_HID];
#pragma unroll
  for (int j = 0; j < F_HID; ++j) acc[j] = 0.0f;

  float reg[32];
  // prologue: prefetch tile 0
  {
    const int k = cbase + kk;
    const bool kin = (k < kend);
#pragma unroll
    for (int i = 0; i < 32; ++i) {
      const int rg = row0 + r0 + 8 * i;
      reg[i] = (kin && rg < N) ? x[(size_t)rg * F_IN + k] : 0.0f;
    }
  }

  for (int k0 = cbase; k0 < kend; k0 += 32) {
    // stage regs -> LDS
#pragma unroll
    for (int i = 0; i < 32; ++i) xs[(r0 + 8 * i) * 33 + kk] = reg[i];
    __syncthreads();
    // prefetch next tile (flies during compute below)
    const int kn = k0 + 32;
    if (kn < kend) {
      const int k = kn + kk;
      const bool kin = (k < kend);
#pragma unroll
      for (int i = 0; i < 32; ++i) {
        const int rg = row0 + r0 + 8 * i;
        reg[i] = (kin && rg < N) ? x[(size_t)rg * F_IN + k] : 0.0f;
      }
    }
    // compute tile k0
    const int kw = min(32, kend - k0);
    const float* __restrict__ wp = W1 + (size_t)k0 * F_HID;
    if (kw == 32) {
#pragma unroll
      for (int c = 0; c < 32; ++c) {
        const float xv = xs[t * 33 + c];
#pragma unroll
        for (int j = 0; j < F_HID; ++j)
          acc[j] = fmaf(xv, wp[c * F_HID + j], acc[j]);
      }
    } else {
      for (int c = 0; c < kw; ++c) {
        const float xv = xs[t * 33 + c];
#pragma unroll
        for (int j = 0; j < F_HID; ++j)
          acc[j] = fmaf(xv, wp[c * F_HID + j], acc[j]);
      }
    }
    __syncthreads();
  }

  if (row < N) {
    float4* __restrict__ pp =
        (float4*)(part + ((size_t)blockIdx.y * N + row) * F_HID);
    pp[0] = make_float4(acc[0], acc[1], acc[2], acc[3]);
    pp[1] = make_float4(acc[4], acc[5], acc[6], acc[7]);
    pp[2] = make_float4(acc[8], acc[9], acc[10], acc[11]);
    pp[3] = make_float4(acc[12], acc[13], acc[14], acc[15]);
  }
}

// ---- reduce K-split partials, scale by dis, pack to bf16 -------------------
__global__ __launch_bounds__(256) void k_red(const float4* __restrict__ part,
                                             const float* __restrict__ dis,
                                             uint2* __restrict__ h1b, int N) {
  const int idx = blockIdx.x * 256 + threadIdx.x;  // over N*4 float4s
  if (idx >= N * 4) return;
  const int row = idx >> 2;
  const size_t stride = (size_t)N * 4;
  float4 s = part[idx];
#pragma unroll
  for (int c = 1; c < KSPLIT; ++c) {
    const float4 p = part[c * stride + idx];
    s.x += p.x; s.y += p.y; s.z += p.z; s.w += p.w;
  }
  const float sc = dis[row];
  uint2 o;
  o.x = (unsigned)f2bf(s.x * sc) | ((unsigned)f2bf(s.y * sc) << 16);
  o.y = (unsigned)f2bf(s.z * sc) | ((unsigned)f2bf(s.w * sc) << 16);
  h1b[idx] = o;
}

// ---- layer1 gather + node update fused: one wave64 per dst node ------------
// lanes = 4 neighbor-groups x 16 features; h1 stored as bf16
__global__ __launch_bounds__(256) void k_agg1n(
    const int* __restrict__ offs, const int* __restrict__ cnt,
    const int* __restrict__ csr, const unsigned short* __restrict__ h1b,
    const float* __restrict__ dis, const float* __restrict__ b1,
    const float* __restrict__ W2, float* __restrict__ h2s, int N) {
  const int lane = threadIdx.x & 63;
  const int i = blockIdx.x * 4 + (threadIdx.x >> 6);
  if (i >= N) return;
  const int nb = lane >> 4;
  const int f = lane & 15;

  const int o0 = offs[i];
  const int cend = o0 + cnt[i];
  int c = o0 + nb;
  float acc = 0.0f;
  for (; c + 4 < cend; c += 8) {
    const int sa = csr[c];
    const int sb = csr[c + 4];
    acc += bf2f(h1b[(size_t)sa * F_HID + f]) +
           bf2f(h1b[(size_t)sb * F_HID + f]);
  }
  if (c < cend) acc += bf2f(h1b[(size_t)csr[c] * F_HID + f]);

  acc += __shfl_xor(acc, 16);
  acc += __shfl_xor(acc, 32);

  const float sd = dis[i];
  const float t =
      fmaxf(fmaf(acc + bf2f(h1b[(size_t)i * F_HID + f]), sd, b1[f]), 0.0f);

  float o[F_OUT];
#pragma unroll
  for (int j = 0; j < F_OUT; ++j) o[j] = t * W2[f * F_OUT + j];
#pragma unroll
  for (int dd = 1; dd < 16; dd <<= 1) {
#pragma unroll
    for (int j = 0; j < F_OUT; ++j) o[j] += __shfl_xor(o[j], dd);
  }
  if (lane == 0) {
    float* __restrict__ hp = h2s + (size_t)i * F_OUT;
#pragma unroll
    for (int j = 0; j < F_OUT; ++j) hp[j] = o[j] * sd;
  }
}

// ---- layer2 gather + bias + log_softmax fused: one wave64 per dst ----------
__global__ __launch_bounds__(256) void k_agg2n(const int* __restrict__ offs,
                                               const int* __restrict__ cnt,
                                               const int* __restrict__ csr,
                                               const float* __restrict__ h2s,
                                               const float* __restrict__ dis,
                                               const float* __restrict__ b2,
                                               float* __restrict__ out, int N) {
  const int lane = threadIdx.x & 63;
  const int i = blockIdx.x * 4 + (threadIdx.x >> 6);
  if (i >= N) return;
  const int nb = lane >> 3;
  const int f = lane & 7;

  const int o0 = offs[i];
  const int cend = o0 + cnt[i];
  int c = o0 + nb;
  float acc = 0.0f;
  for (; c + 8 < cend; c += 16) {
    const int sa = csr[c];
    const int sb = csr[c + 8];
    if (f < F_OUT)
      acc += h2s[(size_t)sa * F_OUT + f] + h2s[(size_t)sb * F_OUT + f];
  }
  if (c < cend && f < F_OUT) acc += h2s[(size_t)csr[c] * F_OUT + f];

  acc += __shfl_xor(acc, 8);
  acc += __shfl_xor(acc, 16);
  acc += __shfl_xor(acc, 32);

  float v = -1e30f;
  if (f < F_OUT)
    v = fmaf(acc + h2s[(size_t)i * F_OUT + f], dis[i], b2[f]);

  float m = v;
  m = fmaxf(m, __shfl_xor(m, 1));
  m = fmaxf(m, __shfl_xor(m, 2));
  m = fmaxf(m, __shfl_xor(m, 4));
  float ex = (f < F_OUT) ? expf(v - m) : 0.0f;
  float sum = ex;
  sum += __shfl_xor(sum, 1);
  sum += __shfl_xor(sum, 2);
  sum += __shfl_xor(sum, 4);
  const float r = v - m - logf(sum);
  if (f < F_OUT) out[(size_t)i * F_OUT + f] = r;
}

extern "C" void kernel_launch(void* const* d_in, const int* in_sizes, int n_in,
                              void* d_out, int out_size, void* d_ws,
                              size_t ws_size, hipStream_t stream) {
  const float* x = (const float*)d_in[0];
  const int* ei = (const int*)d_in[1];
  const float* W1 = (const float*)d_in[2];
  const float* b1 = (const float*)d_in[3];
  const float* W2 = (const float*)d_in[4];
  const float* b2 = (const float*)d_in[5];

  const int N = in_sizes[0] / F_IN;
  const int E = in_sizes[1] / 2;
  const int* src = ei;
  const int* dst = ei + E;

  // ws layout (floats): part[KSPLIT*16N] | h1b[16N bf16] | h2s[7N] | dis[N] |…
  float* part = (float*)d_ws;                               // KSPLIT*16N
  unsigned short* h1b = (unsigned short*)(part + (size_t)KSPLIT * 16 * N);
  float* h2s = (float*)(h1b + (size_t)16 * N);              // 7N
  float* dis = h2s + (size_t)7 * N;                         // N
  int* cnt = (int*)(dis + N);                               // N
  int* offs = cnt + N;                                      // N
  int* cursor = offs + N;                                   // N
  int* bsums = cursor + N;                                  // 1024
  int* csr = (int*)part;  // alias: part fully consumed by k_red before scatter
  float* out = (float*)d_out;

  const int B = 256;
  const int nb_scan = (N + 1023) / 1024;
  const int nrb = (N + 255) / 256;
  const int ne4 = (E + 3) / 4;

  k_zero<<<(N + B - 1) / B, B, 0, stream>>>(cnt, N);
  k_hist<<<(ne4 + B - 1) / B, B, 0, stream>>>(dst, cnt, E);
  k_scan1<<<nb_scan, B, 0, stream>>>(cnt, offs, bsums, N);
  k_scan2<<<1, 1024, 0, stream>>>(bsums, nb_scan);
  k_scan3<<<(N + B - 1) / B, B, 0, stream>>>(offs, cursor, dis, cnt, bsums, N);
  dim3 g1(nrb, KSPLIT);
  k_gemm1<<<g1, 256, 0, stream>>>(x, W1, part, N);
  k_red<<<(N * 4 + B - 1) / B, B, 0, stream>>>((const float4*)part, dis,
                                               (uint2*)h1b, N);
  k_scatter<<<(ne4 + B - 1) / B, B, 0, stream>>>(src, dst, cursor, csr, E);
  k_agg1n<<<(N + 3) / 4, B, 0, stream>>>(offs, cnt, csr, h1b, dis, b1, W2, h2s,
                                         N);
  k_agg2n<<<(N + 3) / 4, B, 0, stream>>>(offs, cnt, csr, h2s, dis, b2, out, N);
}